// Round 1
// baseline (2895.405 us; speedup 1.0000x reference)
//
#include <hip/hip_runtime.h>

// Neural-ODE RK4 over MLP 12->300->100->50->12, B=1024, T=100.
// One block per 4 batch elements (wave w = local batch w).
// All weights resident in LDS (fp32, transposed), W4+biases in registers.

constexpr int BATCH = 1024;
constexpr int T  = 100;
constexpr int D  = 12;
constexpr int H1 = 300;
constexpr int H2 = 100;
constexpr int H3 = 50;
constexpr float NEG = 0.01f;

__device__ __forceinline__ float lrelu(float x) { return x >= 0.0f ? x : NEG * x; }
__device__ __forceinline__ float dot4(float4 a, float4 b) {
    return a.x * b.x + a.y * b.y + a.z * b.z + a.w * b.w;
}

__global__ __launch_bounds__(256, 1)
void node_rk4_kernel(const float* __restrict__ y0, const float* __restrict__ t,
                     const float* __restrict__ W1, const float* __restrict__ b1,
                     const float* __restrict__ W2, const float* __restrict__ b2,
                     const float* __restrict__ W3, const float* __restrict__ b3,
                     const float* __restrict__ W4, const float* __restrict__ b4,
                     float* __restrict__ out)
{
    // LDS budget: 14400 + 120000 + 20000 + 4800 + 1600 + 3*192 = 161,376 B (< 160 KiB)
    __shared__ __align__(16) float sWt1[H1 * D];    // [j][k]  j<300, k<12
    __shared__ __align__(16) float sWt2[H2 * H1];   // [j][k]  j<100, k<300
    __shared__ __align__(16) float sWt3[H3 * H2];   // [j][k]  j<50,  k<100
    __shared__ __align__(16) float bufA[4 * H1];    // h1, then h3 (h1 dead after L2)
    __shared__ __align__(16) float bufB[4 * H2];    // h2
    __shared__ __align__(16) float sx [4 * D];      // current state x
    __shared__ __align__(16) float sxe[4 * D];      // eval point for k2..k4
    __shared__ __align__(16) float sks[4 * D];      // k1 + 2k2 + 2k3 accumulator

    const int tid   = threadIdx.x;
    const int lane  = tid & 63;
    const int bw    = tid >> 6;                 // local batch = wave id (0..3)
    const int batch = blockIdx.x * 4 + bw;

    // ---- stage transposed weights into LDS (one-time) ----
    for (int i = tid; i < H1 * D; i += 256) {         // W1: [12][300] -> Wt1[j][k]
        int k = i / H1, j = i - k * H1;
        sWt1[j * D + k] = W1[i];
    }
    for (int i = tid; i < H1 * H2; i += 256) {        // W2: [300][100] -> Wt2[j][k]
        int k = i / H2, j = i - k * H2;
        sWt2[j * H1 + k] = W2[i];
    }
    for (int i = tid; i < H2 * H3; i += 256) {        // W3: [100][50] -> Wt3[j][k]
        int k = i / H3, j = i - k * H3;
        sWt3[j * H2 + k] = W3[i];
    }

    // ---- per-thread constants in registers ----
    float rb1[5];
#pragma unroll
    for (int c = 0; c < 5; ++c) {
        int j = lane + 64 * c;
        rb1[c] = (j < H1) ? b1[j] : 0.0f;
    }
    const float rb2a = b2[lane];
    const float rb2b = (lane + 64 < H2) ? b2[lane + 64] : 0.0f;
    const float rb3  = (lane < H3) ? b3[lane] : 0.0f;
    const float rb4  = (lane < D)  ? b4[lane] : 0.0f;

    float w4r[H3];                                    // column `lane` of W4 [50][12]
#pragma unroll
    for (int k = 0; k < H3; ++k)
        w4r[k] = (lane < D) ? W4[k * D + lane] : 0.0f;

    // ---- init state x0 = y0[:,0,:], write out[:,0,:] ----
    if (tid < 4 * D) {
        int b = tid / D, j = tid - b * D;
        int g = (blockIdx.x * 4 + b) * (T * D) + j;
        float v = y0[g];
        sx[tid] = v;
        out[g]  = v;
    }
    __syncthreads();

    for (int s = 0; s < T - 1; ++s) {
        const float dt = t[s + 1] - t[s];             // row 0 of t; uniform scalar
        for (int ev = 0; ev < 4; ++ev) {
            const float* xin = (ev == 0) ? sx : sxe;

            // ---- layer 1: D -> H1, lanes cover columns stride 64 ----
            {
                const float4* xp = (const float4*)(xin + bw * D);
                const float4 x0 = xp[0], x1 = xp[1], x2 = xp[2];
#pragma unroll
                for (int c = 0; c < 5; ++c) {
                    int j = lane + 64 * c;
                    if (j < H1) {
                        const float4* wp = (const float4*)(sWt1 + j * D);
                        float acc = rb1[c];
                        acc += dot4(x0, wp[0]);
                        acc += dot4(x1, wp[1]);
                        acc += dot4(x2, wp[2]);
                        bufA[bw * H1 + j] = lrelu(acc);
                    }
                }
            }
            __syncthreads();

            // ---- layer 2: H1 -> H2 (dominant: 77% of FLOPs) ----
            {
                const float4* hp  = (const float4*)(bufA + bw * H1);
                const bool   has2 = (lane + 64) < H2;
                const float4* wp0 = (const float4*)(sWt2 + lane * H1);
                const float4* wp1 = (const float4*)(sWt2 + (has2 ? (lane + 64) : lane) * H1);
                float acc0 = rb2a, acc1 = rb2b;
#pragma unroll 5
                for (int kc = 0; kc < H1 / 4; ++kc) {
                    const float4 h = hp[kc];
                    acc0 += dot4(h, wp0[kc]);
                    if (has2) acc1 += dot4(h, wp1[kc]);
                }
                bufB[bw * H2 + lane] = lrelu(acc0);
                if (has2) bufB[bw * H2 + lane + 64] = lrelu(acc1);
            }
            __syncthreads();

            // ---- layer 3: H2 -> H3 (writes over dead h1 in bufA) ----
            if (lane < H3) {
                const float4* hp = (const float4*)(bufB + bw * H2);
                const float4* wp = (const float4*)(sWt3 + lane * H2);
                float acc = rb3;
#pragma unroll
                for (int kc = 0; kc < H2 / 4; ++kc)
                    acc += dot4(hp[kc], wp[kc]);
                bufA[bw * H1 + lane] = lrelu(acc);
            }
            __syncthreads();

            // ---- layer 4: H3 -> D, fused RK4 update ----
            if (lane < D) {
                const float* hp = bufA + bw * H1;
                float acc = rb4;
#pragma unroll
                for (int k = 0; k < H3; ++k)
                    acc += hp[k] * w4r[k];
                const int bi = bw * D + lane;
                const float xc = sx[bi];
                if (ev == 0) {
                    sks[bi] = acc;
                    sxe[bi] = xc + 0.5f * dt * acc;
                } else if (ev == 1) {
                    sks[bi] += 2.0f * acc;
                    sxe[bi] = xc + 0.5f * dt * acc;
                } else if (ev == 2) {
                    sks[bi] += 2.0f * acc;
                    sxe[bi] = xc + dt * acc;
                } else {
                    const float xn = xc + dt * (1.0f / 6.0f) * (sks[bi] + acc);
                    sx[bi] = xn;
                    out[batch * (T * D) + (s + 1) * D + lane] = xn;
                }
            }
            __syncthreads();
        }
    }
}

extern "C" void kernel_launch(void* const* d_in, const int* in_sizes, int n_in,
                              void* d_out, int out_size, void* d_ws, size_t ws_size,
                              hipStream_t stream) {
    const float* y0 = (const float*)d_in[0];
    const float* t  = (const float*)d_in[1];
    const float* W1 = (const float*)d_in[2];
    const float* b1 = (const float*)d_in[3];
    const float* W2 = (const float*)d_in[4];
    const float* b2 = (const float*)d_in[5];
    const float* W3 = (const float*)d_in[6];
    const float* b3 = (const float*)d_in[7];
    const float* W4 = (const float*)d_in[8];
    const float* b4 = (const float*)d_in[9];
    float* out = (float*)d_out;

    node_rk4_kernel<<<BATCH / 4, 256, 0, stream>>>(y0, t, W1, b1, W2, b2, W3, b3, W4, b4, out);
}

// Round 2
// 1945.694 us; speedup vs baseline: 1.4881x; 1.4881x over previous
//
#include <hip/hip_runtime.h>

// Neural-ODE RK4 over MLP 12->300->100->50->12, B=1024, T=100.
// Block = 4 batch elements, 256 threads (4 waves). Weights LDS-resident.
// L1: column-split across waves (weights read once per CU per eval).
// L2/L3: K-split across waves + cross-wave LDS reduction (weights once/CU/eval).
// W2/W3 stored chunked [c][col][4] -> lanes read consecutive 16B slots: 0 conflicts.

constexpr int BATCH = 1024;
constexpr int T  = 100;
constexpr int D  = 12;
constexpr int H1 = 300;
constexpr int H2 = 100;
constexpr int H3 = 50;
constexpr float NEG = 0.01f;

__device__ __forceinline__ float lrelu(float x) { return x >= 0.0f ? x : NEG * x; }
__device__ __forceinline__ float dot4(float4 a, float4 b) {
    return a.x * b.x + a.y * b.y + a.z * b.z + a.w * b.w;
}

__global__ __launch_bounds__(256, 1)
void node_rk4_kernel(const float* __restrict__ y0, const float* __restrict__ t,
                     const float* __restrict__ W1, const float* __restrict__ b1,
                     const float* __restrict__ W2, const float* __restrict__ b2,
                     const float* __restrict__ W3, const float* __restrict__ b3,
                     const float* __restrict__ W4, const float* __restrict__ b4,
                     float* __restrict__ out)
{
    // LDS: 14400 + 120000 + 20000 + 6400 + 1600 + 3*192 + 600 = 163,576 B
    __shared__ __align__(16) float sW1 [D * H1];       // [k][j]   12x300 (untransposed)
    __shared__ __align__(16) float sW2c[75 * H2 * 4];  // [c][j][4] chunked, conflict-free
    __shared__ __align__(16) float sW3c[25 * H3 * 4];  // [c][j][4]
    __shared__ __align__(16) float uBuf[1600];         // h1 [4][300] | pL2 [4][400] | pL3 [4][200]
    __shared__ __align__(16) float bufB[400];          // h2 [4][100]; h3 [4][56] aliases [0:224)
    __shared__ __align__(16) float sx [48];            // state x       [4][12]
    __shared__ __align__(16) float sxe[48];            // RK4 eval point
    __shared__ __align__(16) float sks[48];            // k1+2k2+2k3 accumulator
    __shared__ __align__(16) float sB2[H2];
    __shared__ __align__(16) float sB3[H3 + 2];

    const int tid = threadIdx.x;
    const int l   = tid & 63;
    const int w   = tid >> 6;                  // wave id 0..3
    const int batch = blockIdx.x * 4 + w;

    // ---- one-time staging ----
    for (int i = tid; i < D * H1; i += 256) sW1[i] = W1[i];
    for (int i = tid; i < H1 * H2; i += 256) {         // W2 [k=300][j=100]
        int k = i / H2, j = i - k * H2;
        sW2c[(k >> 2) * 400 + j * 4 + (k & 3)] = W2[i];
    }
    for (int i = tid; i < H2 * H3; i += 256) {         // W3 [k=100][j=50]
        int k = i / H3, j = i - k * H3;
        sW3c[(k >> 2) * 200 + j * 4 + (k & 3)] = W3[i];
    }
    if (tid < H2) sB2[tid] = b2[tid];
    if (tid < H3) sB3[tid] = b3[tid];

    // ---- per-thread register constants ----
    const int  j0     = w * 75 + l;                    // L1 column (always < 300)
    const bool hasJ1  = (l < 11);                      // second L1 column j0+64
    const float rb1_0 = b1[j0];
    const float rb1_1 = hasJ1 ? b1[j0 + 64] : 0.0f;
    const float rb4   = (l < D) ? b4[l] : 0.0f;
    float w4r[H3];                                     // column l of W4 [50][12]
#pragma unroll
    for (int k = 0; k < H3; ++k)
        w4r[k] = (l < D) ? W4[k * D + l] : 0.0f;

    // ---- init x0 = y0[:,0,:], write out[:,0,:] ----
    if (tid < 4 * D) {
        int b = tid / D, j = tid - b * D;
        int g = (blockIdx.x * 4 + b) * (T * D) + j;
        float v = y0[g];
        sx[tid] = v;
        out[g]  = v;
    }
    __syncthreads();

    for (int s = 0; s < T - 1; ++s) {
        const float dt = t[s + 1] - t[s];              // uniform (t row 0)
        for (int ev = 0; ev < 4; ++ev) {
            const float* xin = ev ? sxe : sx;

            // ===== L1: 12 -> 300, column-split across waves =====
            float a10[4], a11[4];
#pragma unroll
            for (int e = 0; e < 4; ++e) { a10[e] = rb1_0; a11[e] = rb1_1; }
#pragma unroll
            for (int k = 0; k < D; ++k) {
                const float wv0 = sW1[k * H1 + j0];
                const float wv1 = sW1[k * H1 + j0 + (hasJ1 ? 64 : 0)];
#pragma unroll
                for (int e = 0; e < 4; ++e) {
                    const float xv = xin[e * D + k];   // LDS broadcast
                    a10[e] += xv * wv0;
                    a11[e] += xv * wv1;
                }
            }
#pragma unroll
            for (int e = 0; e < 4; ++e) {
                uBuf[e * H1 + j0] = lrelu(a10[e]);
                if (hasJ1) uBuf[e * H1 + j0 + 64] = lrelu(a11[e]);
            }
            __syncthreads();                           // A: h1 ready

            // ===== L2: 300 -> 100, K-split (chunks c == w mod 4) =====
            float a20[4] = {0.f, 0.f, 0.f, 0.f};
            float a21[4] = {0.f, 0.f, 0.f, 0.f};
            const int j2 = l + ((l < 36) ? 64 : 0);    // 2nd column (dup-safe)
#pragma unroll 2
            for (int c = w; c < 75; c += 4) {
                const float4 wv0 = *(const float4*)(sW2c + c * 400 + l  * 4);
                const float4 wv1 = *(const float4*)(sW2c + c * 400 + j2 * 4);
#pragma unroll
                for (int e = 0; e < 4; ++e) {
                    const float4 h = *(const float4*)(uBuf + e * H1 + c * 4);
                    a20[e] += dot4(h, wv0);
                    a21[e] += dot4(h, wv1);
                }
            }
            __syncthreads();                           // B: all h1 reads done
#pragma unroll
            for (int e = 0; e < 4; ++e) {              // partials over dead h1
                uBuf[w * 400 + e * H2 + l] = a20[e];
                if (l < 36) uBuf[w * 400 + e * H2 + l + 64] = a21[e];
            }
            __syncthreads();                           // C: partials visible
            for (int o = tid; o < 400; o += 256) {     // reduce -> h2
                const int e = o / 100, j = o - e * 100;
                float v = sB2[j] + uBuf[o] + uBuf[400 + o] + uBuf[800 + o] + uBuf[1200 + o];
                bufB[o] = lrelu(v);
            }
            __syncthreads();                           // D: h2 ready

            // ===== L3: 100 -> 50, K-split =====
            if (l < H3) {
                float a3[4] = {0.f, 0.f, 0.f, 0.f};
#pragma unroll 2
                for (int c = w; c < 25; c += 4) {
                    const float4 wv = *(const float4*)(sW3c + c * 200 + l * 4);
#pragma unroll
                    for (int e = 0; e < 4; ++e) {
                        const float4 h = *(const float4*)(bufB + e * H2 + c * 4);
                        a3[e] += dot4(h, wv);
                    }
                }
#pragma unroll
                for (int e = 0; e < 4; ++e)            // partials over dead pL2
                    uBuf[w * 200 + e * H3 + l] = a3[e];
            }
            __syncthreads();                           // E: partials visible
            if (tid < 200) {                           // reduce -> h3 (over dead h2)
                const int o = tid, e = o / 50, j = o - e * 50;
                float v = sB3[j] + uBuf[o] + uBuf[200 + o] + uBuf[400 + o] + uBuf[600 + o];
                bufB[e * 56 + j] = lrelu(v);
            }
            __syncthreads();                           // F: h3 ready

            // ===== L4: 50 -> 12 + fused RK4 update (wave w = elem w) =====
            if (l < D) {
                const float* h3 = bufB + w * 56;
                float acc = rb4;
#pragma unroll
                for (int q = 0; q < 12; ++q) {
                    const float4 hv = *(const float4*)(h3 + q * 4);
                    acc += hv.x * w4r[q * 4 + 0] + hv.y * w4r[q * 4 + 1]
                         + hv.z * w4r[q * 4 + 2] + hv.w * w4r[q * 4 + 3];
                }
                acc += h3[48] * w4r[48] + h3[49] * w4r[49];
                const int bi = w * D + l;
                const float xc = sx[bi];
                if (ev == 0) {
                    sks[bi] = acc;
                    sxe[bi] = xc + 0.5f * dt * acc;
                } else if (ev == 1) {
                    sks[bi] += 2.0f * acc;
                    sxe[bi] = xc + 0.5f * dt * acc;
                } else if (ev == 2) {
                    sks[bi] += 2.0f * acc;
                    sxe[bi] = xc + dt * acc;
                } else {
                    const float xn = xc + dt * (1.0f / 6.0f) * (sks[bi] + acc);
                    sx[bi] = xn;
                    out[batch * (T * D) + (s + 1) * D + l] = xn;
                }
            }
            __syncthreads();                           // G: state ready
        }
    }
}

extern "C" void kernel_launch(void* const* d_in, const int* in_sizes, int n_in,
                              void* d_out, int out_size, void* d_ws, size_t ws_size,
                              hipStream_t stream) {
    const float* y0 = (const float*)d_in[0];
    const float* t  = (const float*)d_in[1];
    const float* W1 = (const float*)d_in[2];
    const float* b1 = (const float*)d_in[3];
    const float* W2 = (const float*)d_in[4];
    const float* b2 = (const float*)d_in[5];
    const float* W3 = (const float*)d_in[6];
    const float* b3 = (const float*)d_in[7];
    const float* W4 = (const float*)d_in[8];
    const float* b4 = (const float*)d_in[9];
    float* out = (float*)d_out;

    node_rk4_kernel<<<BATCH / 4, 256, 0, stream>>>(y0, t, W1, b1, W2, b2, W3, b3, W4, b4, out);
}